// Round 1
// baseline (639.269 us; speedup 1.0000x reference)
//
#include <hip/hip_runtime.h>

// HardBinaryVote: votes (63, N) int32 in {0,1}; weights (63,) fp32.
// out[j] = (sum_{v[i][j]==1} w[i]) > (sum_{v[i][j]==0} w[i]) ? 1 : 0  (int32)
//
// Memory-bound streaming kernel: 504 MB read + 8 MB write -> ~81 us floor
// at 6.3 TB/s achievable HBM BW.
//
// CORRECTNESS-CRITICAL: c1/c0 replicate numpy's pairwise_sum for n=63
// (8 accumulators over i=0..55, combine ((r0+r1)+(r2+r3))+((r4+r5)+(r6+r7)),
// then sequential remainder i=56..62) so the fp32 sums are BIT-EXACT vs the
// numpy reference -- the (c1 > c0) sign comparison then cannot flip on
// near-ties. Do NOT compile with -ffast-math / reassociation.

#define NM 63

__global__ __launch_bounds__(256) void hard_binary_vote_kernel(
    const int* __restrict__ votes, const float* __restrict__ wts,
    int* __restrict__ out, int n)
{
    __shared__ float ws[NM];
    if (threadIdx.x < NM) ws[threadIdx.x] = wts[threadIdx.x];
    __syncthreads();

    const size_t t  = (size_t)blockIdx.x * blockDim.x + threadIdx.x;
    const size_t j0 = t * 4;                 // first of 4 samples for this thread
    if (j0 >= (size_t)n) return;

    const size_t row = (size_t)n;            // row stride in elements

    // numpy pairwise accumulators: r[k] sums a[k], a[8+k], ..., a[48+k]
    float r1[8][4], r0[8][4];
#pragma unroll
    for (int k = 0; k < 8; ++k)
#pragma unroll
        for (int s = 0; s < 4; ++s) { r1[k][s] = 0.0f; r0[k][s] = 0.0f; }

    // i = 0..55 in blocks of 8 (0.0f + x == x exactly for x >= 0, so
    // zero-init + accumulate matches numpy's r[k] = a[k] init).
    for (int b = 0; b < 7; ++b) {
#pragma unroll
        for (int k = 0; k < 8; ++k) {
            const int i = 8 * b + k;
            const int4 v = *(const int4*)(votes + (size_t)i * row + j0);
            const float wi = ws[i];
            const int vv[4] = {v.x, v.y, v.z, v.w};
#pragma unroll
            for (int s = 0; s < 4; ++s) {
                r1[k][s] += (vv[s] == 1) ? wi : 0.0f;
                r0[k][s] += (vv[s] == 0) ? wi : 0.0f;
            }
        }
    }

    // numpy combine order
    float c1[4], c0[4];
#pragma unroll
    for (int s = 0; s < 4; ++s) {
        c1[s] = ((r1[0][s] + r1[1][s]) + (r1[2][s] + r1[3][s]))
              + ((r1[4][s] + r1[5][s]) + (r1[6][s] + r1[7][s]));
        c0[s] = ((r0[0][s] + r0[1][s]) + (r0[2][s] + r0[3][s]))
              + ((r0[4][s] + r0[5][s]) + (r0[6][s] + r0[7][s]));
    }

    // remainder i = 56..62, sequential (numpy tail loop)
#pragma unroll
    for (int i = 56; i < NM; ++i) {
        const int4 v = *(const int4*)(votes + (size_t)i * row + j0);
        const float wi = ws[i];
        const int vv[4] = {v.x, v.y, v.z, v.w};
#pragma unroll
        for (int s = 0; s < 4; ++s) {
            c1[s] += (vv[s] == 1) ? wi : 0.0f;
            c0[s] += (vv[s] == 0) ? wi : 0.0f;
        }
    }

    int4 res;
    res.x = (c1[0] > c0[0]) ? 1 : 0;
    res.y = (c1[1] > c0[1]) ? 1 : 0;
    res.z = (c1[2] > c0[2]) ? 1 : 0;
    res.w = (c1[3] > c0[3]) ? 1 : 0;
    *(int4*)(out + j0) = res;
}

extern "C" void kernel_launch(void* const* d_in, const int* in_sizes, int n_in,
                              void* d_out, int out_size, void* d_ws, size_t ws_size,
                              hipStream_t stream)
{
    const int*   votes = (const int*)d_in[0];
    const float* wts   = (const float*)d_in[1];
    int*         out   = (int*)d_out;
    const int n = out_size;                 // N_SAMPLES = 2,000,000 (divisible by 4)

    const int threads  = 256;
    const int nthreads = (n + 3) / 4;       // one thread per 4 samples
    const int blocks   = (nthreads + threads - 1) / threads;

    hipLaunchKernelGGL(hard_binary_vote_kernel, dim3(blocks), dim3(threads), 0, stream,
                       votes, wts, out, n);
}

// Round 2
// 636.929 us; speedup vs baseline: 1.0037x; 1.0037x over previous
//
#include <hip/hip_runtime.h>

// HardBinaryVote: votes (63, N) int32 in {0,1}; weights (63,) fp32.
// out[j] = (sum_{v[i][j]==1} w[i]) > (sum_{v[i][j]==0} w[i]) ? 1 : 0  (int32)
//
// Memory-bound streaming kernel: 504 MB read + 8 MB write -> ~80 us floor at
// the 6.4 TB/s ceiling the harness's own fillBuffer dispatches demonstrate.
//
// R1 -> R2: halved per-thread state (2 samples/thread, int2 loads, 32 accs),
// forced `#pragma unroll 1` on the row-block loop so only 8 loads are in
// flight (R1's fully-unrolled 63x int4 + 64 accs likely spilled VGPRs),
// __launch_bounds__(256,4) for >=16 waves/CU.
//
// CORRECTNESS-CRITICAL (verified absmax 0.0 in R1): c1/c0 replicate numpy's
// pairwise_sum for n=63 (8 accumulators over i=0..55, combine
// ((r0+r1)+(r2+r3))+((r4+r5)+(r6+r7)), then sequential tail i=56..62) so the
// fp32 sums are BIT-EXACT vs the numpy reference -- the (c1 > c0) sign
// comparison then cannot flip on near-ties. Do NOT reassociate / fast-math.

#define NM 63

__global__ __launch_bounds__(256, 4) void hard_binary_vote_kernel(
    const int* __restrict__ votes, const float* __restrict__ wts,
    int* __restrict__ out, int n)
{
    __shared__ float ws[64];
    if (threadIdx.x < NM) ws[threadIdx.x] = wts[threadIdx.x];
    __syncthreads();

    const size_t t  = (size_t)blockIdx.x * blockDim.x + threadIdx.x;
    const size_t j0 = t * 2;                 // 2 samples per thread
    if (j0 >= (size_t)n) return;

    const size_t row = (size_t)n;            // row stride in elements

    // numpy pairwise accumulators: r[k] sums rows k, k+8, ..., k+48
    float r1[8][2], r0[8][2];
#pragma unroll
    for (int k = 0; k < 8; ++k)
#pragma unroll
        for (int s = 0; s < 2; ++s) { r1[k][s] = 0.0f; r0[k][s] = 0.0f; }

    // Rows 0..55 in blocks of 8. unroll 1: keeps only 8 int2 loads in
    // flight per iteration -> ~58 VGPRs total, no spills.
#pragma unroll 1
    for (int b = 0; b < 7; ++b) {
        int2 v[8];
#pragma unroll
        for (int k = 0; k < 8; ++k)
            v[k] = *(const int2*)(votes + (size_t)(8 * b + k) * row + j0);
#pragma unroll
        for (int k = 0; k < 8; ++k) {
            const float wi = ws[8 * b + k];
            r1[k][0] += (v[k].x != 0) ? wi : 0.0f;
            r0[k][0] += (v[k].x == 0) ? wi : 0.0f;
            r1[k][1] += (v[k].y != 0) ? wi : 0.0f;
            r0[k][1] += (v[k].y == 0) ? wi : 0.0f;
        }
    }

    // numpy combine order
    float c1[2], c0[2];
#pragma unroll
    for (int s = 0; s < 2; ++s) {
        c1[s] = ((r1[0][s] + r1[1][s]) + (r1[2][s] + r1[3][s]))
              + ((r1[4][s] + r1[5][s]) + (r1[6][s] + r1[7][s]));
        c0[s] = ((r0[0][s] + r0[1][s]) + (r0[2][s] + r0[3][s]))
              + ((r0[4][s] + r0[5][s]) + (r0[6][s] + r0[7][s]));
    }

    // tail rows 56..62, sequential (numpy tail loop)
    {
        int2 v[7];
#pragma unroll
        for (int i = 0; i < 7; ++i)
            v[i] = *(const int2*)(votes + (size_t)(56 + i) * row + j0);
#pragma unroll
        for (int i = 0; i < 7; ++i) {
            const float wi = ws[56 + i];
            c1[0] += (v[i].x != 0) ? wi : 0.0f;
            c0[0] += (v[i].x == 0) ? wi : 0.0f;
            c1[1] += (v[i].y != 0) ? wi : 0.0f;
            c0[1] += (v[i].y == 0) ? wi : 0.0f;
        }
    }

    int2 res;
    res.x = (c1[0] > c0[0]) ? 1 : 0;
    res.y = (c1[1] > c0[1]) ? 1 : 0;
    *(int2*)(out + j0) = res;
}

extern "C" void kernel_launch(void* const* d_in, const int* in_sizes, int n_in,
                              void* d_out, int out_size, void* d_ws, size_t ws_size,
                              hipStream_t stream)
{
    const int*   votes = (const int*)d_in[0];
    const float* wts   = (const float*)d_in[1];
    int*         out   = (int*)d_out;
    const int n = out_size;                 // N_SAMPLES = 2,000,000 (even)

    const int threads  = 256;
    const int nthreads = (n + 1) / 2;       // one thread per 2 samples
    const int blocks   = (nthreads + threads - 1) / threads;

    hipLaunchKernelGGL(hard_binary_vote_kernel, dim3(blocks), dim3(threads), 0, stream,
                       votes, wts, out, n);
}